// Round 18
// baseline (617.147 us; speedup 1.0000x reference)
//
#include <hip/hip_runtime.h>
#include <hip/hip_bf16.h>
#include <stdint.h>

#define NCn 2000
#define NOn 100000
#define NEn 200000
#define NDST 402000   // dst segs: co@0(NO) oc@100000(NC) eo@102000(NO) oe@202000(NE)
#define NB1 1571      // ceil(402000/256)
// merged fuse grid: course 32, object 1563, enroll 3125
#define NB_C 32
#define NB_CO 1595
#define NB_ALL 4720
// prep1 grid: count 2344 | wgemm 128 | cbias 6
#define P1_CNT 2344
#define P1_WG 2472
#define P1_ALL 2478
// prep2 grid: fill 2344 | packk 248
#define P2_FILL 2344
#define P2_ALL 2592
// gather grid: 402000 pairs x 16 lanes / 256
#define NB_G 25125

typedef __bf16 bf16x8 __attribute__((ext_vector_type(8)));
typedef float f32x4 __attribute__((ext_vector_type(4)));
typedef unsigned short u16x8 __attribute__((ext_vector_type(8)));

__device__ inline unsigned short f2bf(float f) {
  return __builtin_bit_cast(unsigned short, (__bf16)f);
}
__device__ inline float bf2f(unsigned short u) {
  unsigned int x = ((unsigned int)u) << 16;
  return __builtin_bit_cast(float, x);
}
__device__ inline u16x8 cvt8(float4 a, float4 b) {
  u16x8 o;
  o[0] = f2bf(a.x); o[1] = f2bf(a.y); o[2] = f2bf(a.z); o[3] = f2bf(a.w);
  o[4] = f2bf(b.x); o[5] = f2bf(b.y); o[6] = f2bf(b.z); o[7] = f2bf(b.w);
  return o;
}
__device__ inline f32x4 mfma16(bf16x8 a, bf16x8 b, f32x4 c) {
  return __builtin_amdgcn_mfma_f32_16x16x32_bf16(a, b, c, 0, 0, 0);
}
__device__ inline bf16x8 g16(const unsigned short* p) {
  return __builtin_bit_cast(bf16x8, *(const u16x8*)p);
}
__device__ inline float sigm(float x) { return 1.f / (1.f + __expf(-x)); }

// XOR swizzle (ushort-index space), r in [0,64), c in [0,128)
#define XLI(r, c) ((r) * 128 + ((c) ^ (((r) & 7) << 3)))

// ---------------- prep1: count_all | wgemmP2 | cbias (merged dispatch) --------
__global__ __launch_bounds__(256) void prep1(
    const int* __restrict__ s_co, const int* __restrict__ d_co,
    const int* __restrict__ s_oc, const int* __restrict__ d_oc,
    const int* __restrict__ s_eo, const int* __restrict__ d_eo,
    const int* __restrict__ s_oe, const int* __restrict__ d_oe,
    int* __restrict__ cs, int* __restrict__ cd,
    const float* __restrict__ Wco, const float* __restrict__ Woc,
    const float* __restrict__ Weo, const float* __restrict__ Woe,
    const float* __restrict__ GW, const float* __restrict__ WIH,
    float* __restrict__ Pt,
    const float* __restrict__ gate_b, const float* __restrict__ b_ih,
    const float* __restrict__ b_hh, const float* __restrict__ b_co,
    const float* __restrict__ b_oc, const float* __restrict__ b_eo,
    const float* __restrict__ b_oe, float* __restrict__ cb) {
  __shared__ unsigned short Wb[128 * 128];
  __shared__ unsigned short Qb[16][136];
  int blk = blockIdx.x, tid = threadIdx.x;
  if (blk < P1_CNT) {
    int i = blk * 256 + tid;
    if (i < 100000) {
      atomicAdd(&cs[s_co[i]], 1); atomicAdd(&cd[d_co[i]], 1);
    } else if (i < 200000) {
      int e = i - 100000;
      atomicAdd(&cs[2000 + s_oc[e]], 1); atomicAdd(&cd[100000 + d_oc[e]], 1);
    } else if (i < 400000) {
      int e = i - 200000;
      atomicAdd(&cs[102000 + s_eo[e]], 1); atomicAdd(&cd[102000 + d_eo[e]], 1);
    } else if (i < 600000) {
      int e = i - 400000;
      atomicAdd(&cs[302000 + s_oe[e]], 1); atomicAdd(&cd[202000 + d_oe[e]], 1);
    }
  } else if (blk < P1_WG) {
    int bb = blk - P1_CNT;
    int rel = bb >> 5, jt = bb & 31;
    int j0 = jt * 16;
    const float* W = (rel == 0) ? Wco : (rel == 1) ? Woc : (rel == 2) ? Weo : Woe;
    for (int i = tid * 8; i < 16384; i += 2048) {
      float4 a = *(const float4*)&W[i];
      float4 b = *(const float4*)&W[i + 4];
      *(u16x8*)&Wb[i] = cvt8(a, b);
    }
    {
      int row = tid >> 4, c = (tid & 15) * 8;
      int j = j0 + row;
      const float* q = (j < 128) ? &GW[(size_t)j * 384 + c] : &WIH[(size_t)(j - 128) * 128 + c];
      float4 a = *(const float4*)q;
      float4 b = *(const float4*)(q + 4);
      *(u16x8*)&Qb[row][c] = cvt8(a, b);
    }
    __syncthreads();
    int jj = tid & 15, kk = tid >> 4;
    float acc[8] = {};
    for (int m = 0; m < 128; m += 8) {
      u16x8 qv = *(u16x8*)&Qb[jj][m];
#pragma unroll
      for (int i = 0; i < 8; ++i) {
        u16x8 wv = *(u16x8*)&Wb[(kk * 8 + i) * 128 + m];
#pragma unroll
        for (int e = 0; e < 8; ++e)
          acc[i] = fmaf(bf2f(wv[e]), bf2f(qv[e]), acc[i]);
      }
    }
    float* dst = &Pt[((size_t)rel * 512 + j0 + jj) * 128 + kk * 8];
#pragma unroll
    for (int i = 0; i < 8; ++i) dst[i] = acc[i];
  } else {
    int idx = (blk - P1_WG) * 256 + tid;
    if (idx >= 1536) return;
    int type = idx / 512, j = idx & 511;
    float s = 0.f;
    for (int m = 0; m < 128; ++m) {
      float bm = (type == 0) ? b_oc[m] : (type == 1) ? (b_co[m] + b_eo[m]) : b_oe[m];
      float qm = (j < 128) ? GW[j * 384 + m] : WIH[(j - 128) * 128 + m];
      s = fmaf(bm, qm, s);
    }
    if (j < 128) s += gate_b[j];
    else {
      s += b_ih[j - 128];
      if (j < 384) s += b_hh[j - 128];  // b_hh folded for r,z only
    }
    cb[idx] = s;
  }
}

__global__ __launch_bounds__(256) void scan1(const int* __restrict__ in, int* __restrict__ ex,
                                             int* __restrict__ bsum, int n) {
  __shared__ int s[256];
  int t = threadIdx.x, i = blockIdx.x * 256 + t;
  int v = (i < n) ? in[i] : 0;
  s[t] = v;
  for (int d = 1; d < 256; d <<= 1) {
    __syncthreads();
    int x = (t >= d) ? s[t - d] : 0;
    __syncthreads();
    s[t] += x;
  }
  __syncthreads();
  if (i < n) ex[i] = s[t] - v;
  if (t == 255) bsum[blockIdx.x] = s[255];
}

__global__ __launch_bounds__(256) void scan2(const int* __restrict__ bs, int* __restrict__ be, int nb) {
  __shared__ int s[256];
  __shared__ int carry;
  int t = threadIdx.x;
  if (t == 0) carry = 0;
  for (int t0 = 0; t0 < nb; t0 += 256) {
    int i = t0 + t;
    int v = (i < nb) ? bs[i] : 0;
    s[t] = v;
    for (int d = 1; d < 256; d <<= 1) {
      __syncthreads();
      int x = (t >= d) ? s[t - d] : 0;
      __syncthreads();
      s[t] += x;
    }
    __syncthreads();
    int c0 = carry;
    if (i < nb) be[i] = s[t] - v + c0;
    __syncthreads();
    if (t == 0) carry = c0 + s[255];
    __syncthreads();
  }
}

// scan3 + in-place int->float rsqrt conversion of CNT_SRC (scale table)
__global__ __launch_bounds__(256) void scan3(int* __restrict__ off, const int* __restrict__ be,
                                             int* __restrict__ cs_int, int n) {
  int i = blockIdx.x * 256 + threadIdx.x;
  if (i < n) {
    off[i] += be[blockIdx.x];
    int c = cs_int[i];
    ((float*)cs_int)[i] = rsqrtf(fmaxf((float)c, 1.f));
  }
}

// ---------------- prep2: fill_all | packk (merged dispatch) -------------------
__global__ __launch_bounds__(256) void prep2(
    const int* __restrict__ s_co, const int* __restrict__ d_co,
    const int* __restrict__ s_oc, const int* __restrict__ d_oc,
    const int* __restrict__ s_eo, const int* __restrict__ d_eo,
    const int* __restrict__ s_oe, const int* __restrict__ d_oe,
    int* __restrict__ OFF, int* __restrict__ srcs,
    const float* __restrict__ Pt, const float* __restrict__ GW,
    const float* __restrict__ WHH, unsigned short* __restrict__ strm) {
  int blk = blockIdx.x, tid = threadIdx.x;
  if (blk < P2_FILL) {
    int i = blk * 256 + tid;
    if (i < 100000) {
      int pos = atomicAdd(&OFF[d_co[i]], 1);
      srcs[pos] = s_co[i];
    } else if (i < 200000) {
      int e = i - 100000;
      int pos = atomicAdd(&OFF[100000 + d_oc[e]], 1);
      srcs[pos] = s_oc[e];
    } else if (i < 400000) {
      int e = i - 200000;
      int pos = atomicAdd(&OFF[102000 + d_eo[e]], 1);
      srcs[pos] = s_eo[e];
    } else if (i < 600000) {
      int e = i - 400000;
      int pos = atomicAdd(&OFF[202000 + d_oe[e]], 1);
      srcs[pos] = s_oe[e];
    }
  } else {
    // ---- weight stream pack (16KB chunks, K=64; r6/r10-verified layout) ----
    int g = (blk - P2_FILL) * 256 + tid;  // 63488 groups of 8
    if (g >= 63488) return;
    int chunk = g >> 10, within = g & 1023;
    int s = within >> 9, rem = within & 511, tn = rem >> 6, ln = rem & 63;
    int ml = ln & 15, kg = ln >> 4, col = tn * 16 + ml;
    int type, lc;
    if (chunk < 18) { type = 0; lc = chunk; }
    else if (chunk < 44) { type = 1; lc = chunk - 18; }
    else { type = 2; lc = chunk - 44; }
    int nrel = (type == 1) ? 2 : 1;
    int rel0 = (type == 0) ? 1 : (type == 1) ? 0 : 3;
    int rel1 = 2;  // object's second relation (eo)
    int gateN = 2 * nrel + 4;
    int mode, rel = 0, cc = 0, kb = 0;
    if (lc < 2 * nrel) { mode = 0; rel = (lc >> 1) ? rel1 : rel0; kb = (lc & 1) * 64; }
    else if (lc < 2 * nrel + 2) { mode = 1; kb = ((lc - 2 * nrel) & 1) * 64; }
    else if (lc < gateN) { mode = 2; kb = ((lc - 2 * nrel - 2) & 1) * 64; }
    else {
      int l2 = lc - gateN, per = 2 * nrel + 2;
      int slotc = l2 / per;
      cc = (slotc == 0) ? 0 : (slotc == 1) ? 2 : 1;  // stream slots: r, n, z
      int l3 = l2 % per;
      if (l3 < 2) { mode = 4; kb = (l3 & 1) * 64; }                     // WHH first
      else { mode = 3; rel = ((l3 - 2) >> 1) ? rel1 : rel0; kb = ((l3 - 2) & 1) * 64; }
    }
    u16x8 o;
#pragma unroll
    for (int e = 0; e < 8; ++e) {
      int k = kb + s * 32 + kg * 8 + e;
      float v;
      if (mode == 0) v = Pt[((size_t)rel * 512 + col) * 128 + k];
      else if (mode == 1) v = GW[col * 384 + 128 + k];
      else if (mode == 2) v = GW[col * 384 + 256 + k];
      else if (mode == 3) v = Pt[((size_t)rel * 512 + 128 + cc * 128 + col) * 128 + k];
      else v = WHH[(cc * 128 + col) * 128 + k];
      o[e] = f2bf(v);
    }
    *(u16x8*)&strm[(size_t)g * 8] = o;
  }
}

// ---------------- gather_all: edge aggregation, high-occupancy, f32 AGG -------
// 16 lanes per (dst-node, relation) pair; AGG written into d_out regions that
// alias 1:1 with the fuse block's OWN OUT/GOUT rows (AGG_oc<->out_c,
// AGG_co<->out_o, AGG_eo<->g_o, AGG_oe<->out_e), so each fuse block's later
// writes only clobber AGG rows it already consumed into registers.
__global__ __launch_bounds__(256) void gather_all(
    const float* __restrict__ h_c, const float* __restrict__ h_o, const float* __restrict__ h_e,
    const int* __restrict__ CNT_DST, const float* __restrict__ CSF,
    const int* __restrict__ OFF, const int* __restrict__ SRCS,
    float* __restrict__ out) {
  int t = blockIdx.x * 256 + threadIdx.x;
  int pd = t >> 4, ln = t & 15;
  if (pd >= NDST) return;
  const float* H;
  const float* csf;
  float* dst;
  if (pd < 100000) {        // co: dst object, src course
    H = h_c; csf = CSF + 0;
    dst = out + (size_t)(NCn + pd) * 128;                          // out_o
  } else if (pd < 102000) { // oc: dst course, src object
    H = h_o; csf = CSF + 2000;
    dst = out + (size_t)(pd - 100000) * 128;                       // out_c
  } else if (pd < 202000) { // eo: dst object, src enroll
    H = h_e; csf = CSF + 102000;
    dst = out + (size_t)(2 * NCn + NOn + NEn + (pd - 102000)) * 128;  // g_o
  } else {                  // oe: dst enroll, src object
    H = h_o; csf = CSF + 302000;
    dst = out + (size_t)(NCn + NOn + (pd - 202000)) * 128;         // out_e
  }
  int cnt = CNT_DST[pd];
  int end = OFF[pd];
  int c0 = ln * 8;
  float a0 = 0.f, a1 = 0.f, a2 = 0.f, a3 = 0.f, a4 = 0.f, a5 = 0.f, a6 = 0.f, a7 = 0.f;
  for (int e = end - cnt; e < end; e += 2) {
    int s0 = SRCS[e];
    int more = (e + 1 < end);
    int s1 = more ? SRCS[e + 1] : s0;
    float w0 = csf[s0];
    float w1 = more ? csf[s1] : 0.f;
    const float4* p0 = (const float4*)&H[(size_t)s0 * 128 + c0];
    const float4* p1 = (const float4*)&H[(size_t)s1 * 128 + c0];
    float4 x0 = p0[0], y0 = p0[1];
    float4 x1 = p1[0], y1 = p1[1];
    a0 = fmaf(x1.x, w1, fmaf(x0.x, w0, a0));
    a1 = fmaf(x1.y, w1, fmaf(x0.y, w0, a1));
    a2 = fmaf(x1.z, w1, fmaf(x0.z, w0, a2));
    a3 = fmaf(x1.w, w1, fmaf(x0.w, w0, a3));
    a4 = fmaf(y1.x, w1, fmaf(y0.x, w0, a4));
    a5 = fmaf(y1.y, w1, fmaf(y0.y, w0, a5));
    a6 = fmaf(y1.z, w1, fmaf(y0.z, w0, a6));
    a7 = fmaf(y1.w, w1, fmaf(y0.w, w0, a7));
  }
  float iv = rsqrtf(fmaxf((float)cnt, 1.f));
  float4 o0 = make_float4(a0 * iv, a1 * iv, a2 * iv, a3 * iv);
  float4 o1 = make_float4(a4 * iv, a5 * iv, a6 * iv, a7 * iv);
  *(float4*)&dst[c0] = o0;
  *(float4*)&dst[c0 + 4] = o1;
}

// A-fragment from LDS: lane (ml,kg) reads cols kbase + kg*8 .. +7 of its row.
__device__ inline bf16x8 ldsA(const unsigned short* L, int arow, int kbase, int kg) {
  return __builtin_bit_cast(bf16x8, *(const u16x8*)&L[XLI(arow, kbase + kg * 8)]);
}

// ---------------- merged fused GNN layer kernel (gather pre-split) ------------
// 64 nodes/block, 4 waves x 16 rows; type selected per block (wave-uniform).
// Reg-staged double-buffered 16KB weight chunks (1-deep prefetch), __syncthreads
// PHASE. All block inputs (h1, h2, agg) are coalesced streams; no serial gather.
// LDS = 48KB -> 3 blocks/CU; (256,3) caps regs at 170 (no squeeze).
#define PHASE(P, A0, A1, ACC)                                                  \
  do {                                                                         \
    __syncthreads();                                                           \
    {                                                                          \
      int nb_ = (((P) + 1) & 1) * 8192;                                        \
      _Pragma("unroll") for (int j_ = 0; j_ < 4; ++j_)                         \
          *(u16x8*)&wl[nb_ + j_ * 2048 + tid * 8] = rS[j_];                    \
      if ((P) + 2 < NCH) {                                                     \
        const unsigned short* sp_ = stream + (size_t)((P) + 2) * 8192;         \
        _Pragma("unroll") for (int j_ = 0; j_ < 4; ++j_)                       \
            rS[j_] = *(const u16x8*)&sp_[j_ * 2048 + tid * 8];                 \
      }                                                                        \
    }                                                                          \
    {                                                                          \
      int cb_ = ((P) & 1) * 8192;                                              \
      _Pragma("unroll") for (int s_ = 0; s_ < 2; ++s_) {                       \
        bf16x8 a_ = (s_ ? (A1) : (A0));                                        \
        const unsigned short* wb_ = &wl[cb_ + s_ * 4096 + lane * 8];           \
        _Pragma("unroll") for (int tn_ = 0; tn_ < 8; ++tn_) {                  \
          ACC[tn_] = mfma16(a_, g16(wb_ + tn_ * 512), ACC[tn_]);               \
        }                                                                      \
      }                                                                        \
    }                                                                          \
  } while (0)

__global__ __launch_bounds__(256, 3) void fuse_all(
    const float* __restrict__ h1_c, const float* __restrict__ h1_o, const float* __restrict__ h1_e,
    const float* __restrict__ h2_c, const float* __restrict__ h2_o, const float* __restrict__ h2_e,
    const unsigned short* __restrict__ STRM, const float* __restrict__ CBv,
    const float* __restrict__ bhh, float* __restrict__ out) {
  __shared__ __align__(16) unsigned short A1l[8192];   // h1, later fused (16KB)
  __shared__ __align__(16) unsigned short wl[16384];   // 2 x 16KB weight chunks
  int tid = threadIdx.x, lane = tid & 63, w = tid >> 6;
  int ml = lane & 15, kg = lane >> 4;
  int arow = 16 * w + ml;

  // ---- per-block type select (all wave-uniform); course first ----
  float* out_c = out;
  float* out_o = out + (size_t)NCn * 128;
  float* out_e = out + (size_t)(NCn + NOn) * 128;
  float* g_c = out + (size_t)(NCn + NOn + NEn) * 128;
  float* g_o = g_c + (size_t)NCn * 128;
  float* g_e = g_o + (size_t)NOn * 128;
  int b = blockIdx.x;
  const float *H1, *H2;
  const unsigned short* stream;
  const float* cb;
  float *OUT, *GOUT;
  int n, nrel, base;
  if (b < NB_C) {  // course (rel oc); AGG0 aliased at out_c (== OUT)
    base = b * 64; n = NCn; nrel = 1;
    H1 = h1_c; H2 = h2_c;
    stream = STRM; cb = CBv; OUT = out_c; GOUT = g_c;
  } else if (b < NB_CO) {  // object (rel co @ out_o == OUT, rel eo @ g_o == GOUT)
    base = (b - NB_C) * 64; n = NOn; nrel = 2;
    H1 = h1_o; H2 = h2_o;
    stream = STRM + (size_t)18 * 8192; cb = CBv + 512; OUT = out_o; GOUT = g_o;
  } else {  // enroll (rel oe); AGG0 aliased at out_e (== OUT)
    base = (b - NB_CO) * 64; n = NEn; nrel = 1;
    H1 = h1_e; H2 = h2_e;
    stream = STRM + (size_t)44 * 8192; cb = CBv + 1024; OUT = out_e; GOUT = g_e;
  }
  int NCH = (nrel == 1) ? 18 : 26;
  int grow = base + arow;

  // prefetch weight chunk 0 into regs
  u16x8 rS[4];
#pragma unroll
  for (int j = 0; j < 4; ++j) rS[j] = *(const u16x8*)&stream[j * 2048 + tid * 8];

  // stage h1 tile (bf16, swizzled): 64 rows
  for (int i = tid * 8; i < 8192; i += 2048) {
    int row = i >> 7, c = i & 127;
    int r = base + row;
    u16x8 o1 = {0, 0, 0, 0, 0, 0, 0, 0};
    if (r < n) {
      const float4* p1 = (const float4*)&H1[(size_t)r * 128 + c];
      o1 = cvt8(p1[0], p1[1]);
    }
    *(u16x8*)&A1l[XLI(row, c)] = o1;
  }

  // preload h2 A-fragments straight from global (die after gate GEMM)
  bf16x8 h2f[4];
#pragma unroll
  for (int q = 0; q < 4; ++q) {
    u16x8 o = {0, 0, 0, 0, 0, 0, 0, 0};
    if (grow < n) {
      const float* h2r = &H2[(size_t)grow * 128 + q * 32 + kg * 8];
      o = cvt8(*(const float4*)&h2r[0], *(const float4*)&h2r[4]);
    }
    h2f[q] = __builtin_bit_cast(bf16x8, o);
  }

  // preload AGG fragments (f32, aliased at OUT / GOUT; consumed into regs
  // before any of this block's OUT/GOUT writes — values data-depend on them)
  bf16x8 agg0[4], agg1[4];
#pragma unroll
  for (int q = 0; q < 4; ++q) {
    u16x8 o = {0, 0, 0, 0, 0, 0, 0, 0};
    if (grow < n) {
      const float* ap = &OUT[(size_t)grow * 128 + q * 32 + kg * 8];
      o = cvt8(*(const float4*)ap, *(const float4*)(ap + 4));
    }
    agg0[q] = __builtin_bit_cast(bf16x8, o);
  }
  if (nrel == 2) {
#pragma unroll
    for (int q = 0; q < 4; ++q) {
      u16x8 o = {0, 0, 0, 0, 0, 0, 0, 0};
      if (grow < n) {
        const float* ap = &GOUT[(size_t)grow * 128 + q * 32 + kg * 8];
        o = cvt8(*(const float4*)ap, *(const float4*)(ap + 4));
      }
      agg1[q] = __builtin_bit_cast(bf16x8, o);
    }
  }

  // commit chunk 0 to wl buf0; regs <- chunk 1
#pragma unroll
  for (int j = 0; j < 4; ++j) *(u16x8*)&wl[j * 2048 + tid * 8] = rS[j];
#pragma unroll
  for (int j = 0; j < 4; ++j) rS[j] = *(const u16x8*)&stream[8192 + j * 2048 + tid * 8];

  // ---- gate GEMM ----
  f32x4 accg[8] = {};
  int p = 0;
  PHASE(p, agg0[0], agg0[1], accg); ++p;
  PHASE(p, agg0[2], agg0[3], accg); ++p;
  if (nrel == 2) {
    PHASE(p, agg1[0], agg1[1], accg); ++p;
    PHASE(p, agg1[2], agg1[3], accg); ++p;
  }
  PHASE(p, ldsA(A1l, arow, 0, kg), ldsA(A1l, arow, 32, kg), accg); ++p;
  PHASE(p, ldsA(A1l, arow, 64, kg), ldsA(A1l, arow, 96, kg), accg); ++p;
  PHASE(p, h2f[0], h2f[1], accg); ++p;
  PHASE(p, h2f[2], h2f[3], accg); ++p;

  // ---- gate epilogue: g, fused (overwrites own A1l band); h2 re-read coalesced ----
#pragma unroll
  for (int tn = 0; tn < 8; ++tn) {
    int col = tn * 16 + ml;
    float cbv = cb[col];
#pragma unroll
    for (int e = 0; e < 4; ++e) {
      int lrow = 16 * w + kg * 4 + e;
      int node = base + lrow;
      float gv = sigm(accg[tn][e] + cbv);
      float h1v = bf2f(A1l[XLI(lrow, col)]);
      float h2v = 0.f;
      if (node < n) h2v = bf2f(f2bf(H2[(size_t)node * 128 + col]));
      float fu = fmaf(gv, h1v - h2v, h2v);
      A1l[XLI(lrow, col)] = f2bf(fu);
      if (node < n) GOUT[(size_t)node * 128 + col] = gv;
    }
  }

  // ---- GRU slots r, n, z; per slot WHH(fused) phases then PI(agg) phases.
  // Slot n folds r mid-slot; gp holds r then nv (one live packed array).
  unsigned int gp[16];
  for (int s = 0; s < 3; ++s) {
    f32x4 acc[8] = {};
    PHASE(p, ldsA(A1l, arow, 0, kg), ldsA(A1l, arow, 32, kg), acc); ++p;
    PHASE(p, ldsA(A1l, arow, 64, kg), ldsA(A1l, arow, 96, kg), acc); ++p;
    if (s == 1) {
      // acc = gh_n partial; fold r and biases: acc <- cbn + r*(acc+bh)
#pragma unroll
      for (int tn = 0; tn < 8; ++tn) {
        int col = tn * 16 + ml;
        float cbn = cb[384 + col];
        float bh = bhh[256 + col];
#pragma unroll
        for (int e = 0; e < 4; ++e) {
          float rv = bf2f((unsigned short)(gp[tn * 2 + (e >> 1)] >> ((e & 1) * 16)));
          acc[tn][e] = fmaf(rv, acc[tn][e] + bh, cbn);
        }
      }
    }
    PHASE(p, agg0[0], agg0[1], acc); ++p;
    PHASE(p, agg0[2], agg0[3], acc); ++p;
    if (nrel == 2) {
      PHASE(p, agg1[0], agg1[1], acc); ++p;
      PHASE(p, agg1[2], agg1[3], acc); ++p;
    }
    if (s == 0) {  // r -> packed
#pragma unroll
      for (int tn = 0; tn < 8; ++tn) {
        int col = tn * 16 + ml;
        float cbc = cb[128 + col];
        gp[tn * 2] = (unsigned)f2bf(sigm(acc[tn][0] + cbc)) |
                     ((unsigned)f2bf(sigm(acc[tn][1] + cbc)) << 16);
        gp[tn * 2 + 1] = (unsigned)f2bf(sigm(acc[tn][2] + cbc)) |
                         ((unsigned)f2bf(sigm(acc[tn][3] + cbc)) << 16);
      }
    } else if (s == 1) {  // nv = tanh(acc) -> packed (overwrites r)
#pragma unroll
      for (int tn = 0; tn < 8; ++tn) {
        unsigned p0 = 0, p1 = 0;
#pragma unroll
        for (int e = 0; e < 4; ++e) {
          float x = fminf(fmaxf(acc[tn][e], -15.f), 15.f);
          float ex = __expf(2.f * x);
          float nv = (ex - 1.f) / (ex + 1.f);
          unsigned h = (unsigned)f2bf(nv);
          if (e == 0) p0 = h;
          else if (e == 1) p0 |= h << 16;
          else if (e == 2) p1 = h;
          else p1 |= h << 16;
        }
        gp[tn * 2] = p0;
        gp[tn * 2 + 1] = p1;
      }
    } else {  // z + output
#pragma unroll
      for (int tn = 0; tn < 8; ++tn) {
        int col = tn * 16 + ml;
        float cbz = cb[256 + col];
#pragma unroll
        for (int e = 0; e < 4; ++e) {
          int lrow = 16 * w + kg * 4 + e;
          int node = base + lrow;
          float zv = sigm(acc[tn][e] + cbz);
          float nv = bf2f((unsigned short)(gp[tn * 2 + (e >> 1)] >> ((e & 1) * 16)));
          float fu = bf2f(A1l[XLI(lrow, col)]);
          float ht = fmaf(zv, fu - nv, nv);
          ht = fmaxf(ht, 0.f);
          if (node < n) OUT[(size_t)node * 128 + col] = ht;
        }
      }
    }
  }
}

extern "C" void kernel_launch(void* const* d_in, const int* in_sizes, int n_in,
                              void* d_out, int out_size, void* d_ws, size_t ws_size,
                              hipStream_t stream) {
  const float* h1_course = (const float*)d_in[3];
  const float* h1_object = (const float*)d_in[4];
  const float* h1_enroll = (const float*)d_in[5];
  const float* h2_course = (const float*)d_in[6];
  const float* h2_object = (const float*)d_in[7];
  const float* h2_enroll = (const float*)d_in[8];
  const float* h_course = (const float*)d_in[0];
  const float* h_object = (const float*)d_in[1];
  const float* h_enroll = (const float*)d_in[2];
  const int* src_co = (const int*)d_in[9];
  const int* dst_co = (const int*)d_in[10];
  const int* src_oc = (const int*)d_in[11];
  const int* dst_oc = (const int*)d_in[12];
  const int* src_eo = (const int*)d_in[13];
  const int* dst_eo = (const int*)d_in[14];
  const int* src_oe = (const int*)d_in[15];
  const int* dst_oe = (const int*)d_in[16];
  const float* W_co = (const float*)d_in[17];
  const float* b_co = (const float*)d_in[18];
  const float* W_oc = (const float*)d_in[19];
  const float* b_oc = (const float*)d_in[20];
  const float* W_eo = (const float*)d_in[21];
  const float* b_eo = (const float*)d_in[22];
  const float* W_oe = (const float*)d_in[23];
  const float* b_oe = (const float*)d_in[24];
  const float* gate_W = (const float*)d_in[25];
  const float* gate_b = (const float*)d_in[26];
  const float* W_ih = (const float*)d_in[27];
  const float* W_hh = (const float*)d_in[28];
  const float* b_ih = (const float*)d_in[29];
  const float* b_hh = (const float*)d_in[30];

  float* out = (float*)d_out;

  // ws layout (assumes ws_size >= ~9.4 MB, same as prior rounds)
  char* wsb = (char*)d_ws;
  int* CNT_DST = (int*)(wsb + 0);            // 402000
  int* CNT_SRC = (int*)(wsb + 1608000);      // 402000 (ints, then in-place floats)
  int* OFF = (int*)(wsb + 3216000);          // 402000
  int* SRCS = (int*)(wsb + 4824000);         // 600000
  int* BSUM = (int*)(wsb + 7224000);         // 1600
  int* BEXC = (int*)(wsb + 7230400);         // 1600
  float* Pt = (float*)(wsb + 7236800);       // 262144 floats ([rel][j][k])
  float* CBv = (float*)(wsb + 8285376);      // 1536
  unsigned short* STRM = (unsigned short*)(wsb + 8291520);  // 507904 ushorts (62 x 16KB)

  hipMemsetAsync(CNT_DST, 0, 804000 * sizeof(int), stream);

  prep1<<<P1_ALL, 256, 0, stream>>>(
      src_co, dst_co, src_oc, dst_oc, src_eo, dst_eo, src_oe, dst_oe, CNT_SRC, CNT_DST,
      W_co, W_oc, W_eo, W_oe, gate_W, W_ih, Pt,
      gate_b, b_ih, b_hh, b_co, b_oc, b_eo, b_oe, CBv);

  scan1<<<NB1, 256, 0, stream>>>(CNT_DST, OFF, BSUM, NDST);
  scan2<<<1, 256, 0, stream>>>(BSUM, BEXC, NB1);
  scan3<<<NB1, 256, 0, stream>>>(OFF, BEXC, CNT_SRC, NDST);

  prep2<<<P2_ALL, 256, 0, stream>>>(
      src_co, dst_co, src_oc, dst_oc, src_eo, dst_eo, src_oe, dst_oe, OFF, SRCS,
      Pt, gate_W, W_hh, STRM);

  // high-occupancy edge aggregation into f32 AGG (aliased in d_out)
  gather_all<<<NB_G, 256, 0, stream>>>(
      h_course, h_object, h_enroll, CNT_DST, (const float*)CNT_SRC, OFF, SRCS, out);

  // single merged fuse dispatch: course, object, enroll
  fuse_all<<<NB_ALL, 256, 0, stream>>>(
      h1_course, h1_object, h1_enroll, h2_course, h2_object, h2_enroll,
      STRM, CBv, b_hh, out);
}

// Round 19
// 555.406 us; speedup vs baseline: 1.1112x; 1.1112x over previous
//
#include <hip/hip_runtime.h>
#include <hip/hip_bf16.h>
#include <stdint.h>

#define NCn 2000
#define NOn 100000
#define NEn 200000
#define NDST 402000   // dst segs: co@0(NO) oc@100000(NC) eo@102000(NO) oe@202000(NE)
#define NB1 1571      // ceil(402000/256)
// merged fuse grid: course 32, object 1563, enroll 3125 (course first: longest gathers)
#define NB_C 32
#define NB_CO 1595
#define NB_ALL 4720
// prep1 grid: count 2344 | wgemm 128 | cbias 6
#define P1_CNT 2344
#define P1_WG 2472
#define P1_ALL 2478
// prep2 grid: fill 2344 | packk 248
#define P2_FILL 2344
#define P2_ALL 2592

typedef __bf16 bf16x8 __attribute__((ext_vector_type(8)));
typedef float f32x4 __attribute__((ext_vector_type(4)));
typedef unsigned short u16x8 __attribute__((ext_vector_type(8)));

__device__ inline unsigned short f2bf(float f) {
  return __builtin_bit_cast(unsigned short, (__bf16)f);
}
__device__ inline float bf2f(unsigned short u) {
  unsigned int x = ((unsigned int)u) << 16;
  return __builtin_bit_cast(float, x);
}
__device__ inline u16x8 cvt8(float4 a, float4 b) {
  u16x8 o;
  o[0] = f2bf(a.x); o[1] = f2bf(a.y); o[2] = f2bf(a.z); o[3] = f2bf(a.w);
  o[4] = f2bf(b.x); o[5] = f2bf(b.y); o[6] = f2bf(b.z); o[7] = f2bf(b.w);
  return o;
}
__device__ inline f32x4 mfma16(bf16x8 a, bf16x8 b, f32x4 c) {
  return __builtin_amdgcn_mfma_f32_16x16x32_bf16(a, b, c, 0, 0, 0);
}
__device__ inline bf16x8 g16(const unsigned short* p) {
  return __builtin_bit_cast(bf16x8, *(const u16x8*)p);
}
__device__ inline float sigm(float x) { return 1.f / (1.f + __expf(-x)); }

// XOR swizzle (ushort-index space), r in [0,64), c in [0,128)
#define XLI(r, c) ((r) * 128 + ((c) ^ (((r) & 7) << 3)))

// ---------------- prep1: count_all | wgemmP2 | cbias (merged dispatch) --------
__global__ __launch_bounds__(256) void prep1(
    const int* __restrict__ s_co, const int* __restrict__ d_co,
    const int* __restrict__ s_oc, const int* __restrict__ d_oc,
    const int* __restrict__ s_eo, const int* __restrict__ d_eo,
    const int* __restrict__ s_oe, const int* __restrict__ d_oe,
    int* __restrict__ cs, int* __restrict__ cd,
    const float* __restrict__ Wco, const float* __restrict__ Woc,
    const float* __restrict__ Weo, const float* __restrict__ Woe,
    const float* __restrict__ GW, const float* __restrict__ WIH,
    float* __restrict__ Pt,
    const float* __restrict__ gate_b, const float* __restrict__ b_ih,
    const float* __restrict__ b_hh, const float* __restrict__ b_co,
    const float* __restrict__ b_oc, const float* __restrict__ b_eo,
    const float* __restrict__ b_oe, float* __restrict__ cb) {
  __shared__ unsigned short Wb[128 * 128];
  __shared__ unsigned short Qb[16][136];
  int blk = blockIdx.x, tid = threadIdx.x;
  if (blk < P1_CNT) {
    // ---- edge degree counting ----
    int i = blk * 256 + tid;
    if (i < 100000) {
      atomicAdd(&cs[s_co[i]], 1); atomicAdd(&cd[d_co[i]], 1);
    } else if (i < 200000) {
      int e = i - 100000;
      atomicAdd(&cs[2000 + s_oc[e]], 1); atomicAdd(&cd[100000 + d_oc[e]], 1);
    } else if (i < 400000) {
      int e = i - 200000;
      atomicAdd(&cs[102000 + s_eo[e]], 1); atomicAdd(&cd[102000 + d_eo[e]], 1);
    } else if (i < 600000) {
      int e = i - 400000;
      atomicAdd(&cs[302000 + s_oe[e]], 1); atomicAdd(&cd[202000 + d_oe[e]], 1);
    }
  } else if (blk < P1_WG) {
    // ---- Pt[rel][j][k] = sum_m W_rel[k][m] * Q[j][m] ----
    int bb = blk - P1_CNT;
    int rel = bb >> 5, jt = bb & 31;
    int j0 = jt * 16;
    const float* W = (rel == 0) ? Wco : (rel == 1) ? Woc : (rel == 2) ? Weo : Woe;
    for (int i = tid * 8; i < 16384; i += 2048) {
      float4 a = *(const float4*)&W[i];
      float4 b = *(const float4*)&W[i + 4];
      *(u16x8*)&Wb[i] = cvt8(a, b);
    }
    {
      int row = tid >> 4, c = (tid & 15) * 8;
      int j = j0 + row;
      const float* q = (j < 128) ? &GW[(size_t)j * 384 + c] : &WIH[(size_t)(j - 128) * 128 + c];
      float4 a = *(const float4*)q;
      float4 b = *(const float4*)(q + 4);
      *(u16x8*)&Qb[row][c] = cvt8(a, b);
    }
    __syncthreads();
    int jj = tid & 15, kk = tid >> 4;
    float acc[8] = {};
    for (int m = 0; m < 128; m += 8) {
      u16x8 qv = *(u16x8*)&Qb[jj][m];
#pragma unroll
      for (int i = 0; i < 8; ++i) {
        u16x8 wv = *(u16x8*)&Wb[(kk * 8 + i) * 128 + m];
#pragma unroll
        for (int e = 0; e < 8; ++e)
          acc[i] = fmaf(bf2f(wv[e]), bf2f(qv[e]), acc[i]);
      }
    }
    float* dst = &Pt[((size_t)rel * 512 + j0 + jj) * 128 + kk * 8];
#pragma unroll
    for (int i = 0; i < 8; ++i) dst[i] = acc[i];
  } else {
    // ---- colbias ----
    int idx = (blk - P1_WG) * 256 + tid;
    if (idx >= 1536) return;
    int type = idx / 512, j = idx & 511;
    float s = 0.f;
    for (int m = 0; m < 128; ++m) {
      float bm = (type == 0) ? b_oc[m] : (type == 1) ? (b_co[m] + b_eo[m]) : b_oe[m];
      float qm = (j < 128) ? GW[j * 384 + m] : WIH[(j - 128) * 128 + m];
      s = fmaf(bm, qm, s);
    }
    if (j < 128) s += gate_b[j];
    else {
      s += b_ih[j - 128];
      if (j < 384) s += b_hh[j - 128];  // b_hh folded for r,z only
    }
    cb[idx] = s;
  }
}

__global__ __launch_bounds__(256) void scan1(const int* __restrict__ in, int* __restrict__ ex,
                                             int* __restrict__ bsum, int n) {
  __shared__ int s[256];
  int t = threadIdx.x, i = blockIdx.x * 256 + t;
  int v = (i < n) ? in[i] : 0;
  s[t] = v;
  for (int d = 1; d < 256; d <<= 1) {
    __syncthreads();
    int x = (t >= d) ? s[t - d] : 0;
    __syncthreads();
    s[t] += x;
  }
  __syncthreads();
  if (i < n) ex[i] = s[t] - v;
  if (t == 255) bsum[blockIdx.x] = s[255];
}

__global__ __launch_bounds__(256) void scan2(const int* __restrict__ bs, int* __restrict__ be, int nb) {
  __shared__ int s[256];
  __shared__ int carry;
  int t = threadIdx.x;
  if (t == 0) carry = 0;
  for (int t0 = 0; t0 < nb; t0 += 256) {
    int i = t0 + t;
    int v = (i < nb) ? bs[i] : 0;
    s[t] = v;
    for (int d = 1; d < 256; d <<= 1) {
      __syncthreads();
      int x = (t >= d) ? s[t - d] : 0;
      __syncthreads();
      s[t] += x;
    }
    __syncthreads();
    int c0 = carry;
    if (i < nb) be[i] = s[t] - v + c0;
    __syncthreads();
    if (t == 0) carry = c0 + s[255];
    __syncthreads();
  }
}

// scan3 + in-place int->float rsqrt conversion of CNT_SRC (scale table)
__global__ __launch_bounds__(256) void scan3(int* __restrict__ off, const int* __restrict__ be,
                                             int* __restrict__ cs_int, int n) {
  int i = blockIdx.x * 256 + threadIdx.x;
  if (i < n) {
    off[i] += be[blockIdx.x];
    int c = cs_int[i];
    ((float*)cs_int)[i] = rsqrtf(fmaxf((float)c, 1.f));
  }
}

// ---------------- prep2: fill_all | packk (merged dispatch) -------------------
__global__ __launch_bounds__(256) void prep2(
    const int* __restrict__ s_co, const int* __restrict__ d_co,
    const int* __restrict__ s_oc, const int* __restrict__ d_oc,
    const int* __restrict__ s_eo, const int* __restrict__ d_eo,
    const int* __restrict__ s_oe, const int* __restrict__ d_oe,
    int* __restrict__ OFF, int* __restrict__ srcs,
    const float* __restrict__ Pt, const float* __restrict__ GW,
    const float* __restrict__ WHH, unsigned short* __restrict__ strm) {
  int blk = blockIdx.x, tid = threadIdx.x;
  if (blk < P2_FILL) {
    int i = blk * 256 + tid;
    if (i < 100000) {
      int pos = atomicAdd(&OFF[d_co[i]], 1);
      srcs[pos] = s_co[i];
    } else if (i < 200000) {
      int e = i - 100000;
      int pos = atomicAdd(&OFF[100000 + d_oc[e]], 1);
      srcs[pos] = s_oc[e];
    } else if (i < 400000) {
      int e = i - 200000;
      int pos = atomicAdd(&OFF[102000 + d_eo[e]], 1);
      srcs[pos] = s_eo[e];
    } else if (i < 600000) {
      int e = i - 400000;
      int pos = atomicAdd(&OFF[202000 + d_oe[e]], 1);
      srcs[pos] = s_oe[e];
    }
  } else {
    // ---- weight stream pack (16KB chunks, K=64; r6/r10-verified layout) ----
    int g = (blk - P2_FILL) * 256 + tid;  // 63488 groups of 8
    if (g >= 63488) return;
    int chunk = g >> 10, within = g & 1023;
    int s = within >> 9, rem = within & 511, tn = rem >> 6, ln = rem & 63;
    int ml = ln & 15, kg = ln >> 4, col = tn * 16 + ml;
    int type, lc;
    if (chunk < 18) { type = 0; lc = chunk; }
    else if (chunk < 44) { type = 1; lc = chunk - 18; }
    else { type = 2; lc = chunk - 44; }
    int nrel = (type == 1) ? 2 : 1;
    int rel0 = (type == 0) ? 1 : (type == 1) ? 0 : 3;
    int rel1 = 2;  // object's second relation (eo)
    int gateN = 2 * nrel + 4;
    int mode, rel = 0, cc = 0, kb = 0;
    if (lc < 2 * nrel) { mode = 0; rel = (lc >> 1) ? rel1 : rel0; kb = (lc & 1) * 64; }
    else if (lc < 2 * nrel + 2) { mode = 1; kb = ((lc - 2 * nrel) & 1) * 64; }
    else if (lc < gateN) { mode = 2; kb = ((lc - 2 * nrel - 2) & 1) * 64; }
    else {
      int l2 = lc - gateN, per = 2 * nrel + 2;
      int slotc = l2 / per;
      cc = (slotc == 0) ? 0 : (slotc == 1) ? 2 : 1;  // stream slots: r, n, z
      int l3 = l2 % per;
      if (l3 < 2) { mode = 4; kb = (l3 & 1) * 64; }                     // WHH first
      else { mode = 3; rel = ((l3 - 2) >> 1) ? rel1 : rel0; kb = ((l3 - 2) & 1) * 64; }
    }
    u16x8 o;
#pragma unroll
    for (int e = 0; e < 8; ++e) {
      int k = kb + s * 32 + kg * 8 + e;
      float v;
      if (mode == 0) v = Pt[((size_t)rel * 512 + col) * 128 + k];
      else if (mode == 1) v = GW[col * 384 + 128 + k];
      else if (mode == 2) v = GW[col * 384 + 256 + k];
      else if (mode == 3) v = Pt[((size_t)rel * 512 + 128 + cc * 128 + col) * 128 + k];
      else v = WHH[(cc * 128 + col) * 128 + k];
      o[e] = f2bf(v);
    }
    *(u16x8*)&strm[(size_t)g * 8] = o;
  }
}

// ---------------- gather aggregation (4-way pipelined, scalar regs, rsqrt table) ----
__device__ inline void gather_rel(const float* __restrict__ H, const int* __restrict__ cd,
                                  const int* __restrict__ offend, const float* __restrict__ csf,
                                  const int* __restrict__ srcs, int grow, int n, int kg,
                                  bf16x8 out[4]) {
  float ac[4][8];
#pragma unroll
  for (int a = 0; a < 4; ++a)
#pragma unroll
    for (int b = 0; b < 8; ++b) ac[a][b] = 0.f;
  if (grow < n) {
    int c = cd[grow];
    int end = offend[grow];
    for (int e = end - c; e < end; e += 4) {
      int m = end - e;
      int s0 = srcs[e];
      int s1 = (m > 1) ? srcs[e + 1] : s0;
      int s2 = (m > 2) ? srcs[e + 2] : s0;
      int s3 = (m > 3) ? srcs[e + 3] : s0;
      float sc0 = csf[s0];
      float sc1 = (m > 1) ? csf[s1] : 0.f;
      float sc2 = (m > 2) ? csf[s2] : 0.f;
      float sc3 = (m > 3) ? csf[s3] : 0.f;
      const float4* h0 = (const float4*)&H[(size_t)s0 * 128 + kg * 8];
      const float4* h1 = (const float4*)&H[(size_t)s1 * 128 + kg * 8];
      const float4* h2 = (const float4*)&H[(size_t)s2 * 128 + kg * 8];
      const float4* h3 = (const float4*)&H[(size_t)s3 * 128 + kg * 8];
#pragma unroll
      for (int ks = 0; ks < 4; ++ks) {
        float4 a0 = h0[ks * 8], b0 = h0[ks * 8 + 1];
        float4 a1 = h1[ks * 8], b1 = h1[ks * 8 + 1];
        float4 a2 = h2[ks * 8], b2 = h2[ks * 8 + 1];
        float4 a3 = h3[ks * 8], b3 = h3[ks * 8 + 1];
        ac[ks][0] = fmaf(a3.x, sc3, fmaf(a2.x, sc2, fmaf(a1.x, sc1, fmaf(a0.x, sc0, ac[ks][0]))));
        ac[ks][1] = fmaf(a3.y, sc3, fmaf(a2.y, sc2, fmaf(a1.y, sc1, fmaf(a0.y, sc0, ac[ks][1]))));
        ac[ks][2] = fmaf(a3.z, sc3, fmaf(a2.z, sc2, fmaf(a1.z, sc1, fmaf(a0.z, sc0, ac[ks][2]))));
        ac[ks][3] = fmaf(a3.w, sc3, fmaf(a2.w, sc2, fmaf(a1.w, sc1, fmaf(a0.w, sc0, ac[ks][3]))));
        ac[ks][4] = fmaf(b3.x, sc3, fmaf(b2.x, sc2, fmaf(b1.x, sc1, fmaf(b0.x, sc0, ac[ks][4]))));
        ac[ks][5] = fmaf(b3.y, sc3, fmaf(b2.y, sc2, fmaf(b1.y, sc1, fmaf(b0.y, sc0, ac[ks][5]))));
        ac[ks][6] = fmaf(b3.z, sc3, fmaf(b2.z, sc2, fmaf(b1.z, sc1, fmaf(b0.z, sc0, ac[ks][6]))));
        ac[ks][7] = fmaf(b3.w, sc3, fmaf(b2.w, sc2, fmaf(b1.w, sc1, fmaf(b0.w, sc0, ac[ks][7]))));
      }
    }
    float iv = rsqrtf(fmaxf((float)c, 1.f));
#pragma unroll
    for (int ks = 0; ks < 4; ++ks)
#pragma unroll
      for (int b = 0; b < 8; ++b) ac[ks][b] *= iv;
  }
#pragma unroll
  for (int ks = 0; ks < 4; ++ks)
    out[ks] = __builtin_bit_cast(
        bf16x8, cvt8(make_float4(ac[ks][0], ac[ks][1], ac[ks][2], ac[ks][3]),
                     make_float4(ac[ks][4], ac[ks][5], ac[ks][6], ac[ks][7])));
}

// A-fragment from LDS: lane (ml,kg) reads cols kbase + kg*8 .. +7 of its row.
__device__ inline bf16x8 ldsA(const unsigned short* L, int arow, int kbase, int kg) {
  return __builtin_bit_cast(bf16x8, *(const u16x8*)&L[XLI(arow, kbase + kg * 8)]);
}

// ---------------- merged fused GNN layer kernel (r16 final structure) ---------
// 64 nodes/block, 4 waves x 16 rows; type selected per block (wave-uniform).
// Reg-staged double-buffered 16KB weight chunks (1-deep prefetch), __syncthreads
// PHASE. LDS = 48KB -> 3 blocks/CU; (256,3) caps regs at 170 (no squeeze).
#define PHASE(P, A0, A1, ACC)                                                  \
  do {                                                                         \
    __syncthreads();                                                           \
    {                                                                          \
      int nb_ = (((P) + 1) & 1) * 8192;                                        \
      _Pragma("unroll") for (int j_ = 0; j_ < 4; ++j_)                         \
          *(u16x8*)&wl[nb_ + j_ * 2048 + tid * 8] = rS[j_];                    \
      if ((P) + 2 < NCH) {                                                     \
        const unsigned short* sp_ = stream + (size_t)((P) + 2) * 8192;         \
        _Pragma("unroll") for (int j_ = 0; j_ < 4; ++j_)                       \
            rS[j_] = *(const u16x8*)&sp_[j_ * 2048 + tid * 8];                 \
      }                                                                        \
    }                                                                          \
    {                                                                          \
      int cb_ = ((P) & 1) * 8192;                                              \
      _Pragma("unroll") for (int s_ = 0; s_ < 2; ++s_) {                       \
        bf16x8 a_ = (s_ ? (A1) : (A0));                                        \
        const unsigned short* wb_ = &wl[cb_ + s_ * 4096 + lane * 8];           \
        _Pragma("unroll") for (int tn_ = 0; tn_ < 8; ++tn_) {                  \
          ACC[tn_] = mfma16(a_, g16(wb_ + tn_ * 512), ACC[tn_]);               \
        }                                                                      \
      }                                                                        \
    }                                                                          \
  } while (0)

__global__ __launch_bounds__(256, 3) void fuse_all(
    const float* __restrict__ h1_c, const float* __restrict__ h1_o, const float* __restrict__ h1_e,
    const float* __restrict__ h2_c, const float* __restrict__ h2_o, const float* __restrict__ h2_e,
    const float* __restrict__ h_c, const float* __restrict__ h_o, const float* __restrict__ h_e,
    const int* __restrict__ CNT_DST, const float* __restrict__ CSF,
    const int* __restrict__ OFF, const int* __restrict__ SRCS,
    const unsigned short* __restrict__ STRM, const float* __restrict__ CBv,
    const float* __restrict__ bhh, float* __restrict__ out) {
  __shared__ __align__(16) unsigned short A1l[8192];   // h1, later fused (16KB)
  __shared__ __align__(16) unsigned short wl[16384];   // 2 x 16KB weight chunks
  int tid = threadIdx.x, lane = tid & 63, w = tid >> 6;
  int ml = lane & 15, kg = lane >> 4;
  int arow = 16 * w + ml;

  // ---- per-block type select (all wave-uniform); course first ----
  float* out_c = out;
  float* out_o = out + (size_t)NCn * 128;
  float* out_e = out + (size_t)(NCn + NOn) * 128;
  float* g_c = out + (size_t)(NCn + NOn + NEn) * 128;
  float* g_o = g_c + (size_t)NCn * 128;
  float* g_e = g_o + (size_t)NOn * 128;
  int b = blockIdx.x;
  const float *H1, *H2, *Hs0, *Hs1 = nullptr;
  const int *cd0, *off0, *cd1 = nullptr, *off1 = nullptr;
  const float *cs0, *cs1 = nullptr;
  const unsigned short* stream;
  const float* cb;
  float *OUT, *GOUT;
  int n, nrel, base;
  if (b < NB_C) {  // course (rel oc) — longest gathers, schedule first
    base = b * 64; n = NCn; nrel = 1;
    H1 = h1_c; H2 = h2_c; Hs0 = h_o;
    cd0 = CNT_DST + 100000; off0 = OFF + 100000; cs0 = CSF + 2000;
    stream = STRM; cb = CBv; OUT = out_c; GOUT = g_c;
  } else if (b < NB_CO) {  // object (rel co + eo)
    base = (b - NB_C) * 64; n = NOn; nrel = 2;
    H1 = h1_o; H2 = h2_o; Hs0 = h_c;
    cd0 = CNT_DST + 0; off0 = OFF + 0; cs0 = CSF + 0;
    Hs1 = h_e; cd1 = CNT_DST + 102000; off1 = OFF + 102000; cs1 = CSF + 102000;
    stream = STRM + (size_t)18 * 8192; cb = CBv + 512; OUT = out_o; GOUT = g_o;
  } else {  // enroll (rel oe)
    base = (b - NB_CO) * 64; n = NEn; nrel = 1;
    H1 = h1_e; H2 = h2_e; Hs0 = h_o;
    cd0 = CNT_DST + 202000; off0 = OFF + 202000; cs0 = CSF + 302000;
    stream = STRM + (size_t)44 * 8192; cb = CBv + 1024; OUT = out_e; GOUT = g_e;
  }
  int NCH = (nrel == 1) ? 18 : 26;
  int grow = base + arow;

  // prefetch weight chunk 0 into regs
  u16x8 rS[4];
#pragma unroll
  for (int j = 0; j < 4; ++j) rS[j] = *(const u16x8*)&stream[j * 2048 + tid * 8];

  // stage h1 tile (bf16, swizzled): 64 rows
  for (int i = tid * 8; i < 8192; i += 2048) {
    int row = i >> 7, c = i & 127;
    int r = base + row;
    u16x8 o1 = {0, 0, 0, 0, 0, 0, 0, 0};
    if (r < n) {
      const float4* p1 = (const float4*)&H1[(size_t)r * 128 + c];
      o1 = cvt8(p1[0], p1[1]);
    }
    *(u16x8*)&A1l[XLI(row, c)] = o1;
  }

  // preload h2 A-fragments straight from global (die after gate GEMM)
  bf16x8 h2f[4];
#pragma unroll
  for (int q = 0; q < 4; ++q) {
    u16x8 o = {0, 0, 0, 0, 0, 0, 0, 0};
    if (grow < n) {
      const float* h2r = &H2[(size_t)grow * 128 + q * 32 + kg * 8];
      float4 a0 = *(const float4*)&h2r[0];
      float4 a1 = *(const float4*)&h2r[4];
      o = cvt8(a0, a1);
    }
    h2f[q] = __builtin_bit_cast(bf16x8, o);
  }

  // gather-aggregate neighbor features into MFMA A-fragments (4-way pipelined)
  bf16x8 agg0[4], agg1[4];
  gather_rel(Hs0, cd0, off0, cs0, SRCS, grow, n, kg, agg0);
  if (nrel == 2) gather_rel(Hs1, cd1, off1, cs1, SRCS, grow, n, kg, agg1);

  // commit chunk 0 to wl buf0; regs <- chunk 1
#pragma unroll
  for (int j = 0; j < 4; ++j) *(u16x8*)&wl[j * 2048 + tid * 8] = rS[j];
#pragma unroll
  for (int j = 0; j < 4; ++j) rS[j] = *(const u16x8*)&stream[8192 + j * 2048 + tid * 8];

  // ---- gate GEMM ----
  f32x4 accg[8] = {};
  int p = 0;
  PHASE(p, agg0[0], agg0[1], accg); ++p;
  PHASE(p, agg0[2], agg0[3], accg); ++p;
  if (nrel == 2) {
    PHASE(p, agg1[0], agg1[1], accg); ++p;
    PHASE(p, agg1[2], agg1[3], accg); ++p;
  }
  PHASE(p, ldsA(A1l, arow, 0, kg), ldsA(A1l, arow, 32, kg), accg); ++p;
  PHASE(p, ldsA(A1l, arow, 64, kg), ldsA(A1l, arow, 96, kg), accg); ++p;
  PHASE(p, h2f[0], h2f[1], accg); ++p;
  PHASE(p, h2f[2], h2f[3], accg); ++p;

  // ---- gate epilogue: g, fused (overwrites own A1l band); h2 re-read coalesced ----
#pragma unroll
  for (int tn = 0; tn < 8; ++tn) {
    int col = tn * 16 + ml;
    float cbv = cb[col];
#pragma unroll
    for (int e = 0; e < 4; ++e) {
      int lrow = 16 * w + kg * 4 + e;
      int node = base + lrow;
      float gv = sigm(accg[tn][e] + cbv);
      float h1v = bf2f(A1l[XLI(lrow, col)]);
      float h2v = 0.f;
      if (node < n) h2v = bf2f(f2bf(H2[(size_t)node * 128 + col]));
      float fu = fmaf(gv, h1v - h2v, h2v);
      A1l[XLI(lrow, col)] = f2bf(fu);
      if (node < n) GOUT[(size_t)node * 128 + col] = gv;
    }
  }

  // ---- GRU slots r, n, z; per slot WHH(fused) phases then PI(agg) phases.
  // Slot n folds r mid-slot; gp holds r then nv (one live packed array).
  unsigned int gp[16];
  for (int s = 0; s < 3; ++s) {
    f32x4 acc[8] = {};
    PHASE(p, ldsA(A1l, arow, 0, kg), ldsA(A1l, arow, 32, kg), acc); ++p;
    PHASE(p, ldsA(A1l, arow, 64, kg), ldsA(A1l, arow, 96, kg), acc); ++p;
    if (s == 1) {
      // acc = gh_n partial; fold r and biases: acc <- cbn + r*(acc+bh)
#pragma unroll
      for (int tn = 0; tn < 8; ++tn) {
        int col = tn * 16 + ml;
        float cbn = cb[384 + col];
        float bh = bhh[256 + col];
#pragma unroll
        for (int e = 0; e < 4; ++e) {
          float rv = bf2f((unsigned short)(gp[tn * 2 + (e >> 1)] >> ((e & 1) * 16)));
          acc[tn][e] = fmaf(rv, acc[tn][e] + bh, cbn);
        }
      }
    }
    PHASE(p, agg0[0], agg0[1], acc); ++p;
    PHASE(p, agg0[2], agg0[3], acc); ++p;
    if (nrel == 2) {
      PHASE(p, agg1[0], agg1[1], acc); ++p;
      PHASE(p, agg1[2], agg1[3], acc); ++p;
    }
    if (s == 0) {  // r -> packed
#pragma unroll
      for (int tn = 0; tn < 8; ++tn) {
        int col = tn * 16 + ml;
        float cbc = cb[128 + col];
        gp[tn * 2] = (unsigned)f2bf(sigm(acc[tn][0] + cbc)) |
                     ((unsigned)f2bf(sigm(acc[tn][1] + cbc)) << 16);
        gp[tn * 2 + 1] = (unsigned)f2bf(sigm(acc[tn][2] + cbc)) |
                         ((unsigned)f2bf(sigm(acc[tn][3] + cbc)) << 16);
      }
    } else if (s == 1) {  // nv = tanh(acc) -> packed (overwrites r)
#pragma unroll
      for (int tn = 0; tn < 8; ++tn) {
        unsigned p0 = 0, p1 = 0;
#pragma unroll
        for (int e = 0; e < 4; ++e) {
          float x = fminf(fmaxf(acc[tn][e], -15.f), 15.f);
          float ex = __expf(2.f * x);
          float nv = (ex - 1.f) / (ex + 1.f);
          unsigned h = (unsigned)f2bf(nv);
          if (e == 0) p0 = h;
          else if (e == 1) p0 |= h << 16;
          else if (e == 2) p1 = h;
          else p1 |= h << 16;
        }
        gp[tn * 2] = p0;
        gp[tn * 2 + 1] = p1;
      }
    } else {  // z + output
#pragma unroll
      for (int tn = 0; tn < 8; ++tn) {
        int col = tn * 16 + ml;
        float cbz = cb[256 + col];
#pragma unroll
        for (int e = 0; e < 4; ++e) {
          int lrow = 16 * w + kg * 4 + e;
          int node = base + lrow;
          float zv = sigm(acc[tn][e] + cbz);
          float nv = bf2f((unsigned short)(gp[tn * 2 + (e >> 1)] >> ((e & 1) * 16)));
          float fu = bf2f(A1l[XLI(lrow, col)]);
          float ht = fmaf(zv, fu - nv, nv);
          ht = fmaxf(ht, 0.f);
          if (node < n) OUT[(size_t)node * 128 + col] = ht;
        }
      }
    }
  }
}

extern "C" void kernel_launch(void* const* d_in, const int* in_sizes, int n_in,
                              void* d_out, int out_size, void* d_ws, size_t ws_size,
                              hipStream_t stream) {
  const float* h1_course = (const float*)d_in[3];
  const float* h1_object = (const float*)d_in[4];
  const float* h1_enroll = (const float*)d_in[5];
  const float* h2_course = (const float*)d_in[6];
  const float* h2_object = (const float*)d_in[7];
  const float* h2_enroll = (const float*)d_in[8];
  const float* h_course = (const float*)d_in[0];
  const float* h_object = (const float*)d_in[1];
  const float* h_enroll = (const float*)d_in[2];
  const int* src_co = (const int*)d_in[9];
  const int* dst_co = (const int*)d_in[10];
  const int* src_oc = (const int*)d_in[11];
  const int* dst_oc = (const int*)d_in[12];
  const int* src_eo = (const int*)d_in[13];
  const int* dst_eo = (const int*)d_in[14];
  const int* src_oe = (const int*)d_in[15];
  const int* dst_oe = (const int*)d_in[16];
  const float* W_co = (const float*)d_in[17];
  const float* b_co = (const float*)d_in[18];
  const float* W_oc = (const float*)d_in[19];
  const float* b_oc = (const float*)d_in[20];
  const float* W_eo = (const float*)d_in[21];
  const float* b_eo = (const float*)d_in[22];
  const float* W_oe = (const float*)d_in[23];
  const float* b_oe = (const float*)d_in[24];
  const float* gate_W = (const float*)d_in[25];
  const float* gate_b = (const float*)d_in[26];
  const float* W_ih = (const float*)d_in[27];
  const float* W_hh = (const float*)d_in[28];
  const float* b_ih = (const float*)d_in[29];
  const float* b_hh = (const float*)d_in[30];

  float* out = (float*)d_out;

  // ws layout (assumes ws_size >= ~9.4 MB, same as prior rounds)
  char* wsb = (char*)d_ws;
  int* CNT_DST = (int*)(wsb + 0);            // 402000
  int* CNT_SRC = (int*)(wsb + 1608000);      // 402000 (ints, then in-place floats)
  int* OFF = (int*)(wsb + 3216000);          // 402000
  int* SRCS = (int*)(wsb + 4824000);         // 600000
  int* BSUM = (int*)(wsb + 7224000);         // 1600
  int* BEXC = (int*)(wsb + 7230400);         // 1600
  float* Pt = (float*)(wsb + 7236800);       // 262144 floats ([rel][j][k])
  float* CBv = (float*)(wsb + 8285376);      // 1536
  unsigned short* STRM = (unsigned short*)(wsb + 8291520);  // 507904 ushorts (62 x 16KB)

  hipMemsetAsync(CNT_DST, 0, 804000 * sizeof(int), stream);

  prep1<<<P1_ALL, 256, 0, stream>>>(
      src_co, dst_co, src_oc, dst_oc, src_eo, dst_eo, src_oe, dst_oe, CNT_SRC, CNT_DST,
      W_co, W_oc, W_eo, W_oe, gate_W, W_ih, Pt,
      gate_b, b_ih, b_hh, b_co, b_oc, b_eo, b_oe, CBv);

  scan1<<<NB1, 256, 0, stream>>>(CNT_DST, OFF, BSUM, NDST);
  scan2<<<1, 256, 0, stream>>>(BSUM, BEXC, NB1);
  scan3<<<NB1, 256, 0, stream>>>(OFF, BEXC, CNT_SRC, NDST);

  prep2<<<P2_ALL, 256, 0, stream>>>(
      src_co, dst_co, src_oc, dst_oc, src_eo, dst_eo, src_oe, dst_oe, OFF, SRCS,
      Pt, gate_W, W_hh, STRM);

  // single merged fuse dispatch: course blocks first (longest), then object, enroll
  fuse_all<<<NB_ALL, 256, 0, stream>>>(
      h1_course, h1_object, h1_enroll, h2_course, h2_object, h2_enroll,
      h_course, h_object, h_enroll, CNT_DST, (const float*)CNT_SRC, OFF, SRCS,
      STRM, CBv, b_hh, out);
}